// Round 5
// baseline (137.175 us; speedup 1.0000x reference)
//
#include <hip/hip_runtime.h>
#include <hip/hip_bf16.h>
#include <math.h>

#pragma clang fp contract(off)

#define BSZ   16
#define NMAXG 64
#define NAA   8400
#define NCC   80
#define KTOP  13
#define WCAP  512
#define MCMAX 6656
#define CLMAX 13312

// CIoU (clipped at 0) with precomputed ga = w1*h1, pa = w2*h2, da = atan(w2/h2)-atan(w1/h1)
__device__ __forceinline__ float ciou_pre(float gx1, float gy1, float gx2, float gy2,
                                          float px1, float py1, float px2, float py2,
                                          float ga, float pa, float da) {
    const float E = 1e-7f;
    float iw = fminf(gx2, px2) - fmaxf(gx1, px1); iw = fmaxf(iw, 0.0f);
    float ih = fminf(gy2, py2) - fmaxf(gy1, py1); ih = fmaxf(ih, 0.0f);
    float inter = iw * ih;
    float uni = ga + pa - inter + E;
    float iou = inter / uni;
    float cw = fmaxf(gx2, px2) - fminf(gx1, px1);
    float ch = fmaxf(gy2, py2) - fminf(gy1, py1);
    float c2 = cw * cw + ch * ch + E;
    float dx = px1 + px2 - gx1 - gx2;
    float dy = py1 + py2 - gy1 - gy2;
    float rho2 = (dx * dx + dy * dy) / 4.0f;
    float v = 0.4052847345693511f * (da * da);   // 4/pi^2
    float alpha = v / (v - iou + (1.0f + E));
    float r = iou - (rho2 / c2 + v * alpha);
    return fmaxf(r, 0.0f);
}

__device__ __forceinline__ int nthbit(unsigned int m, int k) {
    for (int i = 0; i < k; i++) m &= m - 1;
    return __ffs(m) - 1;
}

// ---- K0 (fused): per-anchor precompute + per-row cost-component maxes over all anchors ----
// grid = BSZ * 33 blocks; block (b, chunk) owns 256 anchors of batch b, loops all 64 rows.
__global__ __launch_bounds__(256) void k_pre(
    const float* __restrict__ pd_bboxes, const float* __restrict__ gt_bboxes,
    float4* __restrict__ precomp, float4* __restrict__ rowpre,
    unsigned int* __restrict__ rowmax_u)
{
    __shared__ float4 rp_s[NMAXG];
    __shared__ unsigned int lmax[NMAXG * 3];

    int b = blockIdx.x / 33, chunk = blockIdx.x % 33;
    int t = threadIdx.x, lane = t & 63;
    int a = chunk * 256 + t;
    bool valid = a < NAA;

    float4 q = make_float4(0.f, 0.f, 0.f, 0.f);
    if (valid) {
        float4 p = ((const float4*)pd_bboxes)[(size_t)b * NAA + a];
        float w2 = p.z - p.x, h2 = p.w - p.y + 1e-7f;
        float r2 = w2 / h2;
        q.x = fminf(w2, h2) / fmaxf(w2, h2);   // pd_r
        q.y = w2 * h2;                         // pa
        q.z = r2;                              // r2
        q.w = atanf(r2);                       // at2
        precomp[(size_t)b * NAA + a] = q;
    }
    if (t < NMAXG) {
        float4 g = ((const float4*)gt_bboxes)[b * NMAXG + t];
        float w1 = g.z - g.x, h1 = g.w - g.y + 1e-7f;
        float r1 = w1 / h1;
        float4 rp;
        rp.x = fminf(w1, h1) / fmaxf(w1, h1);  // gt_r
        rp.y = w1 * h1;                        // ga
        rp.z = r1;                             // r1
        rp.w = atanf(r1);                      // at1
        rp_s[t] = rp;
        if (chunk == 0) rowpre[b * NMAXG + t] = rp;
    }
    for (int k = t; k < NMAXG * 3; k += 256) lmax[k] = 0u;
    __syncthreads();

    for (int r = 0; r < NMAXG; r++) {
        float4 rp = rp_s[r];
        float cs = 0.0f, ca = 0.0f, cw = 0.0f;   // all comps >= 0; 0 never exceeds row max
        if (valid) {
            cs = 1.0f - fabsf(rp.x - q.x) / fmaxf(rp.x, q.x);
            ca = 1.0f - fabsf(rp.y - q.y) / fmaxf(rp.y, q.y);
            cw = fminf(rp.z, q.z) / fmaxf(rp.z, q.z);
        }
        for (int o = 32; o; o >>= 1) {
            cs = fmaxf(cs, __shfl_xor(cs, o));
            ca = fmaxf(ca, __shfl_xor(ca, o));
            cw = fmaxf(cw, __shfl_xor(cw, o));
        }
        if (lane == 0) {   // positive floats: uint-bit order == float order
            atomicMax(&lmax[r * 3 + 0], __float_as_uint(cs));
            atomicMax(&lmax[r * 3 + 1], __float_as_uint(ca));
            atomicMax(&lmax[r * 3 + 2], __float_as_uint(cw));
        }
    }
    __syncthreads();
    for (int k = t; k < NMAXG * 3; k += 256)
        if (lmax[k]) atomicMax(&rowmax_u[b * NMAXG * 3 + k], lmax[k]);
}

// ---- K1: one WAVE per (b,n) row: grid-range candidate enumeration, metric, top-13, claims ----
__global__ __launch_bounds__(256) void k_rows(
    const float* __restrict__ pd_scores, const float* __restrict__ pd_bboxes,
    const int* __restrict__ gt_labels, const float* __restrict__ gt_bboxes,
    const float* __restrict__ mask_gt,
    const float4* __restrict__ precomp, const float4* __restrict__ rowpre,
    const float* __restrict__ rowmax,
    unsigned int* __restrict__ fg,
    int* __restrict__ finaln, float* __restrict__ fnalign, float* __restrict__ fnov,
    int* __restrict__ mc_count, int* __restrict__ mlist,
    int* __restrict__ cl_count, int* __restrict__ clist)
{
    __shared__ unsigned long long keys[4][WCAP];
    __shared__ float ovs[4][WCAP];
    __shared__ int win_a[4][16];
    __shared__ float win_al[4][16], win_ov[4][16];
    __shared__ int nw[4];

    int t = threadIdx.x, wv = t >> 6, lane = t & 63;
    int row = blockIdx.x * 4 + wv;          // rows 0..1023, waves independent (no barriers)
    int b = row >> 6, n = row & 63;

    if (mask_gt[row] <= 0.0f) return;       // masked row selects nothing

    float4 g  = ((const float4*)gt_bboxes)[row];
    float4 rp = rowpre[row];
    float dms = rowmax[row * 3 + 0] + 1e-7f;
    float dma = rowmax[row * 3 + 1] + 1e-7f;
    float dmw = rowmax[row * 3 + 2] + 1e-7f;

    // per-level in-gt index masks; anchors are exact floats (i+0.5)*{8,16,32}
    unsigned int xm[3], ym[3];
    int xlo[3], ylo[3], cx[3], cy[3];
    {
        const int LS[3] = {8, 16, 32};
        const int LN[3] = {80, 40, 20};
        #pragma unroll
        for (int l = 0; l < 3; l++) {
            float sf = (float)LS[l], inv = 1.0f / (float)LS[l];
            int nn = LN[l];
            int xl = (int)floorf(g.x * inv - 0.5f) - 1; if (xl < 0) xl = 0;
            int xh = (int)floorf(g.z * inv - 0.5f) + 1; if (xh > nn - 1) xh = nn - 1;
            int yl = (int)floorf(g.y * inv - 0.5f) - 1; if (yl < 0) yl = 0;
            int yh = (int)floorf(g.w * inv - 0.5f) + 1; if (yh > nn - 1) yh = nn - 1;
            bool ok = false;
            if (lane < 32) {
                int i = xl + lane;
                if (i <= xh) {
                    float ax = ((float)i + 0.5f) * sf;
                    ok = (ax - g.x > 1e-9f) && (g.z - ax > 1e-9f);  // reference float test
                }
            } else {
                int i = yl + (lane - 32);
                if (i <= yh) {
                    float ay = ((float)i + 0.5f) * sf;
                    ok = (ay - g.y > 1e-9f) && (g.w - ay > 1e-9f);
                }
            }
            unsigned long long bal = __ballot(ok);
            xm[l] = (unsigned int)bal; ym[l] = (unsigned int)(bal >> 32);
            xlo[l] = xl; ylo[l] = yl; cx[l] = __popc(xm[l]); cy[l] = __popc(ym[l]);
        }
    }
    int c0 = cx[0] * cy[0], c1 = cx[1] * cy[1], c2 = cx[2] * cy[2];
    int cnt = c0 + c1 + c2;                 // bound ~430 (gwh <= 140) < WCAP
    if (cnt > WCAP) cnt = WCAP;

    // metric at candidates (= exactly the in-gt anchors)
    int lbl = gt_labels[row];
    const float* sc = pd_scores + (size_t)b * NAA * NCC + lbl;
    const float4* pb = (const float4*)pd_bboxes + (size_t)b * NAA;
    const float4* pc = precomp + (size_t)b * NAA;
    int mpos = 0;
    for (int jb = 0; jb < cnt; jb += 64) {  // uniform trip count for ballot
        int j = jb + lane;
        bool act = j < cnt;
        float align = 0.0f;
        if (act) {
            int j2, XLO, YLO, CX, NN, BB; unsigned int XM, YM;
            if (j < c0)           { j2 = j;           XM = xm[0]; YM = ym[0]; XLO = xlo[0]; YLO = ylo[0]; CX = cx[0]; NN = 80; BB = 0; }
            else if (j < c0 + c1) { j2 = j - c0;      XM = xm[1]; YM = ym[1]; XLO = xlo[1]; YLO = ylo[1]; CX = cx[1]; NN = 40; BB = 6400; }
            else                  { j2 = j - c0 - c1; XM = xm[2]; YM = ym[2]; XLO = xlo[2]; YLO = ylo[2]; CX = cx[2]; NN = 20; BB = 8000; }
            int iyi = j2 / CX;
            int ixi = j2 - iyi * CX;
            int ix = XLO + nthbit(XM, ixi);
            int iy = YLO + nthbit(YM, iyi);
            int a = BB + iy * NN + ix;
            float4 p = pb[a];
            float4 q = pc[a];
            float cs = 1.0f - fabsf(rp.x - q.x) / fmaxf(rp.x, q.x);
            float ca = 1.0f - fabsf(rp.y - q.y) / fmaxf(rp.y, q.y);
            float cw = fminf(rp.z, q.z) / fmaxf(rp.z, q.z);
            float cost = ((cs / dms + cw / dmw) + ca / dma) / 3.0f;
            cost = fmaxf(cost, 0.0f);
            float ov = ciou_pre(g.x, g.y, g.z, g.w, p.x, p.y, p.z, p.w,
                                rp.y, q.y, q.w - rp.w);
            float s = sc[(size_t)a * NCC];
            float o2 = ov * ov, o3 = o2 * ov, ov6 = o3 * o3;
            align = (s * ov6) * cost;
            keys[wv][j] = ((unsigned long long)__float_as_uint(align) << 32)
                        | (unsigned long long)(0xFFFFFFFFu - (unsigned)a);
            ovs[wv][j] = ov;
        }
        unsigned long long bal = __ballot(align > 0.0f);
        mpos += __popcll(bal);              // wave-uniform
    }

    int bA = b * NAA;
    int nwin;
    if (mpos >= KTOP) {
        // 13 argmax rounds (value desc, index asc = lax.top_k tie-break); winners all positive
        for (int k = 0; k < KTOP; k++) {
            unsigned long long best = 0ull;
            for (int jb = 0; jb < cnt; jb += 64) {
                int j = jb + lane;
                if (j < cnt) { unsigned long long kk = keys[wv][j]; best = kk > best ? kk : best; }
            }
            for (int o = 32; o; o >>= 1) {
                unsigned long long ot = __shfl_xor(best, o);
                best = ot > best ? ot : best;
            }
            for (int jb = 0; jb < cnt; jb += 64) {
                int j = jb + lane;
                if (j < cnt && keys[wv][j] == best) {   // exactly one j (index embedded)
                    keys[wv][j] = 0ull;
                    win_a[wv][k]  = (int)(0xFFFFFFFFu - (unsigned)(best & 0xFFFFFFFFull));
                    win_al[wv][k] = __uint_as_float((unsigned)(best >> 32));
                    win_ov[wv][k] = ovs[wv][j];
                }
            }
        }
        nwin = KTOP;
    } else {
        // <13 positives: all positives + lowest-index zero anchors of the whole row
        // (only in-gt zeros survive the later mask); zero anchor a selected iff
        // (a - #positives_with_idx<a) < Z.
        if (lane == 0) nw[wv] = 0;
        int Z = KTOP - mpos;
        for (int jb = 0; jb < cnt; jb += 64) {
            int j = jb + lane;
            if (j < cnt) {
                unsigned long long kk = keys[wv][j];
                int a = (int)(0xFFFFFFFFu - (unsigned)(kk & 0xFFFFFFFFull));
                bool sel;
                if ((kk >> 32) != 0ull) {
                    sel = true;
                } else {
                    int pcb = 0;
                    for (int j2 = 0; j2 < cnt; j2++) {
                        unsigned long long k2 = keys[wv][j2];
                        if ((k2 >> 32) != 0ull) {
                            int a2 = (int)(0xFFFFFFFFu - (unsigned)(k2 & 0xFFFFFFFFull));
                            if (a2 < a) pcb++;
                        }
                    }
                    sel = (a - pcb) < Z;
                }
                if (sel) {
                    int p = atomicAdd(&nw[wv], 1);
                    win_a[wv][p]  = a;
                    win_al[wv][p] = __uint_as_float((unsigned)(kk >> 32));
                    win_ov[wv][p] = ovs[wv][j];
                }
            }
        }
        nwin = nw[wv];
    }

    // parallel claim: lanes 0..nwin-1 concurrent fg atomics; one list atomic per wave
    bool isclaim = false, ismulti = false;
    int gi = 0;
    if (lane < nwin) {
        gi = bA + win_a[wv][lane];
        unsigned old = atomicAdd(&fg[gi], 1u);
        if (old == 0u) {
            finaln[gi] = n; fnalign[gi] = win_al[wv][lane]; fnov[gi] = win_ov[wv][lane];
            isclaim = true;
        } else if (old == 1u) {
            ismulti = true;
        }
    }
    unsigned long long cb = __ballot(isclaim);
    unsigned long long mb = __ballot(ismulti);
    int cbase = 0, mbase = 0;
    if (lane == 0) {
        if (cb) cbase = atomicAdd(cl_count, __popcll(cb));
        if (mb) mbase = atomicAdd(mc_count, __popcll(mb));
    }
    cbase = __shfl(cbase, 0);
    mbase = __shfl(mbase, 0);
    unsigned long long below = (lane == 0) ? 0ull : (~0ull >> (64 - lane));
    if (isclaim) clist[cbase + __popcll(cb & below)] = gi;
    if (ismulti) mlist[mbase + __popcll(mb & below)] = gi;
}

// ---- K2: one wave per multi-claimed anchor; 64 gts across 64 lanes ----
__global__ __launch_bounds__(256) void k_multi(
    const float* __restrict__ pd_scores, const float* __restrict__ pd_bboxes,
    const int* __restrict__ gt_labels, const float* __restrict__ gt_bboxes,
    const float4* __restrict__ precomp, const float4* __restrict__ rowpre,
    const float* __restrict__ rowmax, const int* __restrict__ mc_count,
    const int* __restrict__ mlist,
    int* __restrict__ finaln, float* __restrict__ fnalign, float* __restrict__ fnov)
{
    int wave = threadIdx.x >> 6, lane = threadIdx.x & 63;
    int nwaves = gridDim.x << 2;
    int count = *mc_count;
    for (int w = (blockIdx.x << 2) + wave; w < count; w += nwaves) {
        int gi = mlist[w];                          // b*NAA + a
        int b = gi / NAA;
        int rowb = (b << 6) + lane;                 // lane = gt index n
        const float4 p  = ((const float4*)pd_bboxes)[gi];
        const float4 q  = precomp[gi];              // pd_r, pa, r2, at2
        const float4 g  = ((const float4*)gt_bboxes)[rowb];
        const float4 rp = rowpre[rowb];             // gt_r, ga, r1, at1
        float ov = ciou_pre(g.x, g.y, g.z, g.w, p.x, p.y, p.z, p.w,
                            rp.y, q.y, q.w - rp.w);
        // argmax over n, first max wins: value desc, index asc
        unsigned long long key = ((unsigned long long)__float_as_uint(ov) << 32)
                               | (unsigned long long)(63 - lane);
        unsigned long long best = key;
        for (int o = 32; o; o >>= 1) {
            unsigned long long ot = __shfl_xor(best, o);
            best = ot > best ? ot : best;
        }
        int nstar = 63 - (int)(best & 63ull);
        if (lane == nstar) {
            float cs = 1.0f - fabsf(rp.x - q.x) / fmaxf(rp.x, q.x);
            float ca = 1.0f - fabsf(rp.y - q.y) / fmaxf(rp.y, q.y);
            float cw = fminf(rp.z, q.z) / fmaxf(rp.z, q.z);
            const float* rm = rowmax + rowb * 3;
            float cost = ((cs / (rm[0] + 1e-7f) + cw / (rm[2] + 1e-7f)) + ca / (rm[1] + 1e-7f)) / 3.0f;
            cost = fmaxf(cost, 0.0f);
            int lbl = gt_labels[rowb];
            float s = pd_scores[(size_t)gi * NCC + lbl];
            float o2 = ov * ov, o3 = o2 * ov, ov6 = o3 * o3;
            finaln[gi] = nstar;
            fnalign[gi] = (s * ov6) * cost;
            fnov[gi] = ov;
        }
    }
}

// ---- K3: claimed-list pass: per-row pos_align / pos_ov maxes from final assignments ----
__global__ __launch_bounds__(256) void k_post(
    const int* __restrict__ cl_count, const int* __restrict__ clist,
    const int* __restrict__ finaln, const float* __restrict__ fnalign,
    const float* __restrict__ fnov,
    unsigned int* __restrict__ pos_align, unsigned int* __restrict__ pos_ov)
{
    int count = *cl_count;
    int i = blockIdx.x * 256 + threadIdx.x;
    if (i >= count) return;
    int gi = clist[i];
    int b = gi / NAA;
    int nf = finaln[gi];
    int r = (b << 6) + nf;
    atomicMax(&pos_align[r], __float_as_uint(fnalign[gi]));   // all values >= 0
    atomicMax(&pos_ov[r], __float_as_uint(fnov[gi]));
}

// ---- K4: write all outputs (labels, bboxes, full score rows incl. zeros, fg_mask) ----
__global__ __launch_bounds__(256) void k_out(
    const int* __restrict__ gt_labels, const float* __restrict__ gt_bboxes,
    const int* __restrict__ finaln, const float* __restrict__ fnalign,
    const unsigned int* __restrict__ pos_align, const unsigned int* __restrict__ pos_ov,
    float* __restrict__ out)
{
    int i = blockIdx.x * 256 + threadIdx.x;   // b*NAA + a
    if (i >= BSZ * NAA) return;
    int b = i / NAA;
    int nf = finaln[i];
    int tgt = (nf >= 0) ? nf : 0;             // argmax of all-zero column = 0
    int lbl = gt_labels[(b << 6) + tgt];
    float4 g = ((const float4*)gt_bboxes)[(b << 6) + tgt];

    out[i] = (float)lbl;                                          // target_labels
    ((float4*)(out + (size_t)BSZ * NAA))[i] = g;                  // target_bboxes

    float* srow = out + (size_t)BSZ * NAA * 5 + (size_t)i * NCC;  // target_scores row
    float4 z; z.x = 0.0f; z.y = 0.0f; z.z = 0.0f; z.w = 0.0f;
    #pragma unroll
    for (int c4 = 0; c4 < NCC / 4; c4++) ((float4*)srow)[c4] = z;

    float* ofg = out + (size_t)BSZ * NAA * (5 + NCC);             // fg_mask
    if (nf >= 0) {
        float pa = __uint_as_float(pos_align[(b << 6) + nf]);
        float po = __uint_as_float(pos_ov[(b << 6) + nf]);
        srow[lbl] = (fnalign[i] * po) / (pa + 1e-9f);
        ofg[i] = 1.0f;
    } else {
        ofg[i] = 0.0f;
    }
}

extern "C" void kernel_launch(void* const* d_in, const int* in_sizes, int n_in,
                              void* d_out, int out_size, void* d_ws, size_t ws_size,
                              hipStream_t stream)
{
    const float* pd_scores = (const float*)d_in[0];
    const float* pd_bboxes = (const float*)d_in[1];
    const int*   gt_labels = (const int*)d_in[3];
    const float* gt_bboxes = (const float*)d_in[4];
    const float* mask_gt   = (const float*)d_in[5];
    float* out = (float*)d_out;

    char* ws = (char*)d_ws;
    const size_t NBA = (size_t)BSZ * NAA * 4;                 // 537600 B per per-anchor array
    size_t off = 0;
    float4*       precomp = (float4*)(ws + off); off += (size_t)BSZ * NAA * 16;   // 2150400
    float4*       rowpre  = (float4*)(ws + off); off += BSZ * NMAXG * 16;         // 16384
    unsigned int* fg      = (unsigned int*)(ws + off); off += NBA;
    int*          finaln  = (int*)(ws + off);          off += NBA;
    float*        fnalign = (float*)(ws + off);        off += NBA;
    float*        fnov    = (float*)(ws + off);        off += NBA;
    unsigned int* posal   = (unsigned int*)(ws + off); off += 4096;
    unsigned int* posov   = (unsigned int*)(ws + off); off += 4096;
    unsigned int* rowmax  = (unsigned int*)(ws + off); off += 12288;
    int*          mc_count= (int*)(ws + off);
    int*          cl_count= (int*)(ws + off + 4);      off += 256;
    int*          mlist   = (int*)(ws + off);          off += MCMAX * 4;
    int*          clist   = (int*)(ws + off);          off += CLMAX * 4;

    // per-call re-init (harness does not re-poison between replays)
    hipMemsetAsync(fg, 0, NBA, stream);
    hipMemsetAsync(finaln, 0xFF, NBA, stream);                // -1
    hipMemsetAsync(posal, 0, 8192 + 12288, stream);           // posal + posov + rowmax
    hipMemsetAsync(mc_count, 0, 8, stream);                   // both counters

    k_pre<<<BSZ * 33, 256, 0, stream>>>(pd_bboxes, gt_bboxes, precomp, rowpre, rowmax);
    k_rows<<<BSZ * NMAXG / 4, 256, 0, stream>>>(pd_scores, pd_bboxes, gt_labels,
                                                gt_bboxes, mask_gt, precomp, rowpre,
                                                (const float*)rowmax, fg,
                                                finaln, fnalign, fnov,
                                                mc_count, mlist, cl_count, clist);
    k_multi<<<256, 256, 0, stream>>>(pd_scores, pd_bboxes, gt_labels, gt_bboxes,
                                     precomp, rowpre, (const float*)rowmax,
                                     mc_count, mlist, finaln, fnalign, fnov);
    k_post<<<CLMAX / 256, 256, 0, stream>>>(cl_count, clist, finaln, fnalign, fnov,
                                            posal, posov);
    int grid = (BSZ * NAA + 255) / 256;
    k_out<<<grid, 256, 0, stream>>>(gt_labels, gt_bboxes, finaln, fnalign, posal, posov, out);
}

// Round 6
// 95.056 us; speedup vs baseline: 1.4431x; 1.4431x over previous
//
#include <hip/hip_runtime.h>
#include <hip/hip_bf16.h>
#include <math.h>

#pragma clang fp contract(off)

#define BSZ   16
#define NMAXG 64
#define NAA   8400
#define NCC   80
#define KTOP  13
#define WCAP  512
#define MCMAX 6656
#define CLMAX 13312
#define NCH   40            // anchor chunks per batch for k_pre
#define CHA   (NAA / NCH)   // 210 anchors per chunk

// CIoU (clipped at 0) with precomputed ga = w1*h1, pa = w2*h2, da = atan(w2/h2)-atan(w1/h1)
__device__ __forceinline__ float ciou_pre(float gx1, float gy1, float gx2, float gy2,
                                          float px1, float py1, float px2, float py2,
                                          float ga, float pa, float da) {
    const float E = 1e-7f;
    float iw = fminf(gx2, px2) - fmaxf(gx1, px1); iw = fmaxf(iw, 0.0f);
    float ih = fminf(gy2, py2) - fmaxf(gy1, py1); ih = fmaxf(ih, 0.0f);
    float inter = iw * ih;
    float uni = ga + pa - inter + E;
    float iou = inter / uni;
    float cw = fmaxf(gx2, px2) - fminf(gx1, px1);
    float ch = fmaxf(gy2, py2) - fminf(gy1, py1);
    float c2 = cw * cw + ch * ch + E;
    float dx = px1 + px2 - gx1 - gx2;
    float dy = py1 + py2 - gy1 - gy2;
    float rho2 = (dx * dx + dy * dy) / 4.0f;
    float v = 0.4052847345693511f * (da * da);   // 4/pi^2
    float alpha = v / (v - iou + (1.0f + E));
    float r = iou - (rho2 / c2 + v * alpha);
    return fmaxf(r, 0.0f);
}

__device__ __forceinline__ int nthbit(unsigned int m, int k) {
    for (int i = 0; i < k; i++) m &= m - 1;
    return __ffs(m) - 1;
}

// ---- K0: per-anchor precompute + per-row cost maxes; lane = row, no per-pair shuffles ----
// grid = BSZ * NCH; block (b, c) owns anchors [c*CHA, (c+1)*CHA) of batch b.
__global__ __launch_bounds__(256) void k_pre(
    const float* __restrict__ pd_bboxes, const float* __restrict__ gt_bboxes,
    float4* __restrict__ precomp, float4* __restrict__ rowpre,
    unsigned int* __restrict__ rowmax_u)
{
    __shared__ float sr[CHA], sa[CHA], sq[CHA];     // pd_r, pa, r2 per chunk anchor
    __shared__ float rpx[NMAXG], rpy[NMAXG], rpz[NMAXG];
    __shared__ unsigned int lmax[NMAXG * 3];

    int b = blockIdx.x / NCH, c = blockIdx.x % NCH;
    int t = threadIdx.x, wv = t >> 6, lane = t & 63;
    int base = c * CHA;

    for (int j = t; j < CHA; j += 256) {
        int a = base + j;
        float4 p = ((const float4*)pd_bboxes)[(size_t)b * NAA + a];
        float w2 = p.z - p.x, h2 = p.w - p.y + 1e-7f;
        float r2 = w2 / h2;
        float pr = fminf(w2, h2) / fmaxf(w2, h2);
        float pa = w2 * h2;
        float4 q; q.x = pr; q.y = pa; q.z = r2; q.w = atanf(r2);
        precomp[(size_t)b * NAA + a] = q;
        sr[j] = pr; sa[j] = pa; sq[j] = r2;
    }
    if (t < NMAXG) {
        float4 g = ((const float4*)gt_bboxes)[b * NMAXG + t];
        float w1 = g.z - g.x, h1 = g.w - g.y + 1e-7f;
        float r1 = w1 / h1;
        float4 rp;
        rp.x = fminf(w1, h1) / fmaxf(w1, h1);
        rp.y = w1 * h1;
        rp.z = r1;
        rp.w = atanf(r1);
        if (c == 0) rowpre[b * NMAXG + t] = rp;
        rpx[t] = rp.x; rpy[t] = rp.y; rpz[t] = rp.z;
    }
    if (t < NMAXG * 3) lmax[t] = 0u;
    __syncthreads();

    // lane = row; waves stride the chunk's anchors (wave-uniform LDS addr = broadcast)
    float rx = rpx[lane], ry = rpy[lane], rz = rpz[lane];
    float ms = 0.0f, ma = 0.0f, mw = 0.0f;   // all comps in [0,1]
    for (int j = wv; j < CHA; j += 4) {
        float vr = sr[j], va = sa[j], vq = sq[j];
        float cs = 1.0f - fabsf(rx - vr) / fmaxf(rx, vr);
        float ca = 1.0f - fabsf(ry - va) / fmaxf(ry, va);
        float cw = fminf(rz, vq) / fmaxf(rz, vq);
        ms = fmaxf(ms, cs); ma = fmaxf(ma, ca); mw = fmaxf(mw, cw);
    }
    atomicMax(&lmax[lane * 3 + 0], __float_as_uint(ms));   // positive floats: bit order = value order
    atomicMax(&lmax[lane * 3 + 1], __float_as_uint(ma));
    atomicMax(&lmax[lane * 3 + 2], __float_as_uint(mw));
    __syncthreads();
    if (t < NMAXG * 3 && lmax[t]) atomicMax(&rowmax_u[b * NMAXG * 3 + t], lmax[t]);
}

// ---- K1: one WAVE per (b,n) row: grid-range candidate enumeration, metric, top-13, claims ----
__global__ __launch_bounds__(256) void k_rows(
    const float* __restrict__ pd_scores, const float* __restrict__ pd_bboxes,
    const int* __restrict__ gt_labels, const float* __restrict__ gt_bboxes,
    const float* __restrict__ mask_gt,
    const float4* __restrict__ precomp, const float4* __restrict__ rowpre,
    const float* __restrict__ rowmax,
    unsigned int* __restrict__ fg,
    int* __restrict__ finaln, float* __restrict__ fnalign, float* __restrict__ fnov,
    int* __restrict__ mc_count, int* __restrict__ mlist,
    int* __restrict__ cl_count, int* __restrict__ clist)
{
    __shared__ unsigned long long keys[4][WCAP];
    __shared__ float ovs[4][WCAP];
    __shared__ int win_a[4][16];
    __shared__ float win_al[4][16], win_ov[4][16];
    __shared__ int nw[4];

    int t = threadIdx.x, wv = t >> 6, lane = t & 63;
    int row = blockIdx.x * 4 + wv;          // waves independent (no barriers)
    int b = row >> 6, n = row & 63;

    if (mask_gt[row] <= 0.0f) return;       // masked row selects nothing

    float4 g  = ((const float4*)gt_bboxes)[row];
    float4 rp = rowpre[row];
    float dms = rowmax[row * 3 + 0] + 1e-7f;
    float dma = rowmax[row * 3 + 1] + 1e-7f;
    float dmw = rowmax[row * 3 + 2] + 1e-7f;

    // per-level in-gt index masks; anchors are exact floats (i+0.5)*{8,16,32}
    unsigned int xm[3], ym[3];
    int xlo[3], ylo[3], cx[3], cy[3];
    {
        const int LS[3] = {8, 16, 32};
        const int LN[3] = {80, 40, 20};
        #pragma unroll
        for (int l = 0; l < 3; l++) {
            float sf = (float)LS[l], inv = 1.0f / (float)LS[l];
            int nn = LN[l];
            int xl = (int)floorf(g.x * inv - 0.5f) - 1; if (xl < 0) xl = 0;
            int xh = (int)floorf(g.z * inv - 0.5f) + 1; if (xh > nn - 1) xh = nn - 1;
            int yl = (int)floorf(g.y * inv - 0.5f) - 1; if (yl < 0) yl = 0;
            int yh = (int)floorf(g.w * inv - 0.5f) + 1; if (yh > nn - 1) yh = nn - 1;
            bool ok = false;
            if (lane < 32) {
                int i = xl + lane;
                if (i <= xh) {
                    float ax = ((float)i + 0.5f) * sf;
                    ok = (ax - g.x > 1e-9f) && (g.z - ax > 1e-9f);  // reference float test
                }
            } else {
                int i = yl + (lane - 32);
                if (i <= yh) {
                    float ay = ((float)i + 0.5f) * sf;
                    ok = (ay - g.y > 1e-9f) && (g.w - ay > 1e-9f);
                }
            }
            unsigned long long bal = __ballot(ok);
            xm[l] = (unsigned int)bal; ym[l] = (unsigned int)(bal >> 32);
            xlo[l] = xl; ylo[l] = yl; cx[l] = __popc(xm[l]); cy[l] = __popc(ym[l]);
        }
    }
    int c0 = cx[0] * cy[0], c1 = cx[1] * cy[1], c2 = cx[2] * cy[2];
    int cnt = c0 + c1 + c2;                 // bound ~430 (gwh <= 140) < WCAP
    if (cnt > WCAP) cnt = WCAP;

    // metric at candidates (= exactly the in-gt anchors)
    int lbl = gt_labels[row];
    const float* sc = pd_scores + (size_t)b * NAA * NCC + lbl;
    const float4* pb = (const float4*)pd_bboxes + (size_t)b * NAA;
    const float4* pc = precomp + (size_t)b * NAA;
    int mpos = 0;
    for (int jb = 0; jb < cnt; jb += 64) {  // uniform trip count for ballot
        int j = jb + lane;
        bool act = j < cnt;
        float align = 0.0f;
        if (act) {
            int j2, XLO, YLO, CX, NN, BB; unsigned int XM, YM;
            if (j < c0)           { j2 = j;           XM = xm[0]; YM = ym[0]; XLO = xlo[0]; YLO = ylo[0]; CX = cx[0]; NN = 80; BB = 0; }
            else if (j < c0 + c1) { j2 = j - c0;      XM = xm[1]; YM = ym[1]; XLO = xlo[1]; YLO = ylo[1]; CX = cx[1]; NN = 40; BB = 6400; }
            else                  { j2 = j - c0 - c1; XM = xm[2]; YM = ym[2]; XLO = xlo[2]; YLO = ylo[2]; CX = cx[2]; NN = 20; BB = 8000; }
            int iyi = j2 / CX;
            int ixi = j2 - iyi * CX;
            int ix = XLO + nthbit(XM, ixi);
            int iy = YLO + nthbit(YM, iyi);
            int a = BB + iy * NN + ix;
            float4 p = pb[a];
            float4 q = pc[a];
            float cs = 1.0f - fabsf(rp.x - q.x) / fmaxf(rp.x, q.x);
            float ca = 1.0f - fabsf(rp.y - q.y) / fmaxf(rp.y, q.y);
            float cw = fminf(rp.z, q.z) / fmaxf(rp.z, q.z);
            float cost = ((cs / dms + cw / dmw) + ca / dma) / 3.0f;
            cost = fmaxf(cost, 0.0f);
            float ov = ciou_pre(g.x, g.y, g.z, g.w, p.x, p.y, p.z, p.w,
                                rp.y, q.y, q.w - rp.w);
            float s = sc[(size_t)a * NCC];
            float o2 = ov * ov, o3 = o2 * ov, ov6 = o3 * o3;
            align = (s * ov6) * cost;
            keys[wv][j] = ((unsigned long long)__float_as_uint(align) << 32)
                        | (unsigned long long)(0xFFFFFFFFu - (unsigned)a);
            ovs[wv][j] = ov;
        }
        unsigned long long bal = __ballot(align > 0.0f);
        mpos += __popcll(bal);              // wave-uniform
    }

    int bA = b * NAA;
    int nwin;
    if (mpos >= KTOP) {
        // 13 argmax rounds (value desc, index asc = lax.top_k tie-break); winners all positive
        for (int k = 0; k < KTOP; k++) {
            unsigned long long best = 0ull;
            for (int jb = 0; jb < cnt; jb += 64) {
                int j = jb + lane;
                if (j < cnt) { unsigned long long kk = keys[wv][j]; best = kk > best ? kk : best; }
            }
            for (int o = 32; o; o >>= 1) {
                unsigned long long ot = __shfl_xor(best, o);
                best = ot > best ? ot : best;
            }
            for (int jb = 0; jb < cnt; jb += 64) {
                int j = jb + lane;
                if (j < cnt && keys[wv][j] == best) {   // exactly one j (index embedded)
                    keys[wv][j] = 0ull;
                    win_a[wv][k]  = (int)(0xFFFFFFFFu - (unsigned)(best & 0xFFFFFFFFull));
                    win_al[wv][k] = __uint_as_float((unsigned)(best >> 32));
                    win_ov[wv][k] = ovs[wv][j];
                }
            }
        }
        nwin = KTOP;
    } else {
        // <13 positives: all positives + lowest-index zero anchors of the whole row
        // (only in-gt zeros survive the later mask); zero anchor a selected iff
        // (a - #positives_with_idx<a) < Z.
        if (lane == 0) nw[wv] = 0;
        int Z = KTOP - mpos;
        for (int jb = 0; jb < cnt; jb += 64) {
            int j = jb + lane;
            if (j < cnt) {
                unsigned long long kk = keys[wv][j];
                int a = (int)(0xFFFFFFFFu - (unsigned)(kk & 0xFFFFFFFFull));
                bool sel;
                if ((kk >> 32) != 0ull) {
                    sel = true;
                } else {
                    int pcb = 0;
                    for (int j2 = 0; j2 < cnt; j2++) {
                        unsigned long long k2 = keys[wv][j2];
                        if ((k2 >> 32) != 0ull) {
                            int a2 = (int)(0xFFFFFFFFu - (unsigned)(k2 & 0xFFFFFFFFull));
                            if (a2 < a) pcb++;
                        }
                    }
                    sel = (a - pcb) < Z;
                }
                if (sel) {
                    int p = atomicAdd(&nw[wv], 1);
                    win_a[wv][p]  = a;
                    win_al[wv][p] = __uint_as_float((unsigned)(kk >> 32));
                    win_ov[wv][p] = ovs[wv][j];
                }
            }
        }
        nwin = nw[wv];
    }

    // parallel claim: lanes 0..nwin-1 concurrent fg atomics; one list atomic per wave
    bool isclaim = false, ismulti = false;
    int gi = 0;
    if (lane < nwin) {
        gi = bA + win_a[wv][lane];
        unsigned old = atomicAdd(&fg[gi], 1u);
        if (old == 0u) {
            finaln[gi] = n; fnalign[gi] = win_al[wv][lane]; fnov[gi] = win_ov[wv][lane];
            isclaim = true;
        } else if (old == 1u) {
            ismulti = true;
        }
    }
    unsigned long long cb = __ballot(isclaim);
    unsigned long long mb = __ballot(ismulti);
    int cbase = 0, mbase = 0;
    if (lane == 0) {
        if (cb) cbase = atomicAdd(cl_count, __popcll(cb));
        if (mb) mbase = atomicAdd(mc_count, __popcll(mb));
    }
    cbase = __shfl(cbase, 0);
    mbase = __shfl(mbase, 0);
    unsigned long long below = (lane == 0) ? 0ull : (~0ull >> (64 - lane));
    if (isclaim) clist[cbase + __popcll(cb & below)] = gi;
    if (ismulti) mlist[mbase + __popcll(mb & below)] = gi;
}

// ---- K2 (fused k_multi + k_post): disjoint gi sets -> no ordering needed ----
__global__ __launch_bounds__(256) void k_fin(
    const float* __restrict__ pd_scores, const float* __restrict__ pd_bboxes,
    const int* __restrict__ gt_labels, const float* __restrict__ gt_bboxes,
    const float4* __restrict__ precomp, const float4* __restrict__ rowpre,
    const float* __restrict__ rowmax, const unsigned int* __restrict__ fg,
    const int* __restrict__ mc_count, const int* __restrict__ mlist,
    const int* __restrict__ cl_count, const int* __restrict__ clist,
    int* __restrict__ finaln, float* __restrict__ fnalign, float* __restrict__ fnov,
    unsigned int* __restrict__ pos_align, unsigned int* __restrict__ pos_ov)
{
    int lane = threadIdx.x & 63;

    // multi-claimed anchors: one wave each; 64 gts across 64 lanes
    int gwv = (blockIdx.x << 2) + (threadIdx.x >> 6);
    int nwv = gridDim.x << 2;
    int mc = *mc_count;
    for (int w = gwv; w < mc; w += nwv) {
        int gi = mlist[w];                          // b*NAA + a
        int b = gi / NAA;
        int rowb = (b << 6) + lane;                 // lane = gt index n
        const float4 p  = ((const float4*)pd_bboxes)[gi];
        const float4 q  = precomp[gi];              // pd_r, pa, r2, at2
        const float4 g  = ((const float4*)gt_bboxes)[rowb];
        const float4 rp = rowpre[rowb];             // gt_r, ga, r1, at1
        float ov = ciou_pre(g.x, g.y, g.z, g.w, p.x, p.y, p.z, p.w,
                            rp.y, q.y, q.w - rp.w);
        // argmax over n, first max wins: value desc, index asc
        unsigned long long key = ((unsigned long long)__float_as_uint(ov) << 32)
                               | (unsigned long long)(63 - lane);
        unsigned long long best = key;
        for (int o = 32; o; o >>= 1) {
            unsigned long long ot = __shfl_xor(best, o);
            best = ot > best ? ot : best;
        }
        int nstar = 63 - (int)(best & 63ull);
        if (lane == nstar) {
            float cs = 1.0f - fabsf(rp.x - q.x) / fmaxf(rp.x, q.x);
            float ca = 1.0f - fabsf(rp.y - q.y) / fmaxf(rp.y, q.y);
            float cw = fminf(rp.z, q.z) / fmaxf(rp.z, q.z);
            const float* rm = rowmax + rowb * 3;
            float cost = ((cs / (rm[0] + 1e-7f) + cw / (rm[2] + 1e-7f)) + ca / (rm[1] + 1e-7f)) / 3.0f;
            cost = fmaxf(cost, 0.0f);
            int lbl = gt_labels[rowb];
            float s = pd_scores[(size_t)gi * NCC + lbl];
            float o2 = ov * ov, o3 = o2 * ov, ov6 = o3 * o3;
            float align = (s * ov6) * cost;
            finaln[gi] = nstar;
            fnalign[gi] = align;
            atomicMax(&pos_align[rowb], __float_as_uint(align));
            atomicMax(&pos_ov[rowb], __float_as_uint(ov));
        }
    }

    // single-claimed anchors (fg==1): per-row pos maxes from k_rows-written values
    int gt = blockIdx.x * 256 + threadIdx.x;
    int gs = gridDim.x * 256;
    int cl = *cl_count;
    for (int i = gt; i < cl; i += gs) {
        int gi = clist[i];
        if (fg[gi] == 1u) {
            int b = gi / NAA;
            int r = (b << 6) + finaln[gi];
            atomicMax(&pos_align[r], __float_as_uint(fnalign[gi]));
            atomicMax(&pos_ov[r], __float_as_uint(fnov[gi]));
        }
    }
}

// ---- K3: write all outputs (labels, bboxes, full score rows incl. zeros, fg_mask) ----
__global__ __launch_bounds__(256) void k_out(
    const int* __restrict__ gt_labels, const float* __restrict__ gt_bboxes,
    const unsigned int* __restrict__ fg,
    const int* __restrict__ finaln, const float* __restrict__ fnalign,
    const unsigned int* __restrict__ pos_align, const unsigned int* __restrict__ pos_ov,
    float* __restrict__ out)
{
    int i = blockIdx.x * 256 + threadIdx.x;   // b*NAA + a
    if (i >= BSZ * NAA) return;
    int b = i / NAA;
    int nf = (fg[i] > 0u) ? finaln[i] : -1;
    int tgt = (nf >= 0) ? nf : 0;             // argmax of all-zero column = 0
    int lbl = gt_labels[(b << 6) + tgt];
    float4 g = ((const float4*)gt_bboxes)[(b << 6) + tgt];

    out[i] = (float)lbl;                                          // target_labels
    ((float4*)(out + (size_t)BSZ * NAA))[i] = g;                  // target_bboxes

    float* srow = out + (size_t)BSZ * NAA * 5 + (size_t)i * NCC;  // target_scores row
    float4 z; z.x = 0.0f; z.y = 0.0f; z.z = 0.0f; z.w = 0.0f;
    #pragma unroll
    for (int c4 = 0; c4 < NCC / 4; c4++) ((float4*)srow)[c4] = z;

    float* ofg = out + (size_t)BSZ * NAA * (5 + NCC);             // fg_mask
    if (nf >= 0) {
        float pa = __uint_as_float(pos_align[(b << 6) + nf]);
        float po = __uint_as_float(pos_ov[(b << 6) + nf]);
        srow[lbl] = (fnalign[i] * po) / (pa + 1e-9f);
        ofg[i] = 1.0f;
    } else {
        ofg[i] = 0.0f;
    }
}

extern "C" void kernel_launch(void* const* d_in, const int* in_sizes, int n_in,
                              void* d_out, int out_size, void* d_ws, size_t ws_size,
                              hipStream_t stream)
{
    const float* pd_scores = (const float*)d_in[0];
    const float* pd_bboxes = (const float*)d_in[1];
    const int*   gt_labels = (const int*)d_in[3];
    const float* gt_bboxes = (const float*)d_in[4];
    const float* mask_gt   = (const float*)d_in[5];
    float* out = (float*)d_out;

    char* ws = (char*)d_ws;
    const size_t NBA = (size_t)BSZ * NAA * 4;                 // 537600 B per per-anchor array
    size_t off = 0;
    float4*       precomp = (float4*)(ws + off); off += (size_t)BSZ * NAA * 16;   // 2150400
    float4*       rowpre  = (float4*)(ws + off); off += BSZ * NMAXG * 16;         // 16384
    unsigned int* fg      = (unsigned int*)(ws + off); off += NBA;
    int*          finaln  = (int*)(ws + off);          off += NBA;
    float*        fnalign = (float*)(ws + off);        off += NBA;
    float*        fnov    = (float*)(ws + off);        off += NBA;
    // contiguous zero-init region: posal | posov | rowmax | counters
    unsigned int* posal   = (unsigned int*)(ws + off); off += 4096;
    unsigned int* posov   = (unsigned int*)(ws + off); off += 4096;
    unsigned int* rowmax  = (unsigned int*)(ws + off); off += 12288;
    int*          mc_count= (int*)(ws + off);
    int*          cl_count= (int*)(ws + off + 4);      off += 256;
    int*          mlist   = (int*)(ws + off);          off += MCMAX * 4;
    int*          clist   = (int*)(ws + off);          off += CLMAX * 4;

    // per-call re-init (harness does not re-poison between replays)
    hipMemsetAsync(fg, 0, NBA, stream);
    hipMemsetAsync(posal, 0, 4096 + 4096 + 12288 + 256, stream);  // posal..counters

    k_pre<<<BSZ * NCH, 256, 0, stream>>>(pd_bboxes, gt_bboxes, precomp, rowpre, rowmax);
    k_rows<<<BSZ * NMAXG / 4, 256, 0, stream>>>(pd_scores, pd_bboxes, gt_labels,
                                                gt_bboxes, mask_gt, precomp, rowpre,
                                                (const float*)rowmax, fg,
                                                finaln, fnalign, fnov,
                                                mc_count, mlist, cl_count, clist);
    k_fin<<<64, 256, 0, stream>>>(pd_scores, pd_bboxes, gt_labels, gt_bboxes,
                                  precomp, rowpre, (const float*)rowmax, fg,
                                  mc_count, mlist, cl_count, clist,
                                  finaln, fnalign, fnov, posal, posov);
    int grid = (BSZ * NAA + 255) / 256;
    k_out<<<grid, 256, 0, stream>>>(gt_labels, gt_bboxes, fg, finaln, fnalign,
                                    posal, posov, out);
}

// Round 7
// 88.653 us; speedup vs baseline: 1.5473x; 1.0722x over previous
//
#include <hip/hip_runtime.h>
#include <hip/hip_bf16.h>
#include <math.h>

#pragma clang fp contract(off)

#define BSZ   16
#define NMAXG 64
#define NAA   8400
#define NCC   80
#define KTOP  13
#define WCAP  512
#define MCMAX 6656
#define CLMAX 13312
#define NCH   40            // anchor chunks per batch for k_pre
#define CHA   (NAA / NCH)   // 210 anchors per chunk

// CIoU (clipped at 0) with precomputed ga = w1*h1, pa = w2*h2, da = atan(w2/h2)-atan(w1/h1)
__device__ __forceinline__ float ciou_pre(float gx1, float gy1, float gx2, float gy2,
                                          float px1, float py1, float px2, float py2,
                                          float ga, float pa, float da) {
    const float E = 1e-7f;
    float iw = fminf(gx2, px2) - fmaxf(gx1, px1); iw = fmaxf(iw, 0.0f);
    float ih = fminf(gy2, py2) - fmaxf(gy1, py1); ih = fmaxf(ih, 0.0f);
    float inter = iw * ih;
    float uni = ga + pa - inter + E;
    float iou = inter / uni;
    float cw = fmaxf(gx2, px2) - fminf(gx1, px1);
    float ch = fmaxf(gy2, py2) - fminf(gy1, py1);
    float c2 = cw * cw + ch * ch + E;
    float dx = px1 + px2 - gx1 - gx2;
    float dy = py1 + py2 - gy1 - gy2;
    float rho2 = (dx * dx + dy * dy) / 4.0f;
    float v = 0.4052847345693511f * (da * da);   // 4/pi^2
    float alpha = v / (v - iou + (1.0f + E));
    float r = iou - (rho2 / c2 + v * alpha);
    return fmaxf(r, 0.0f);
}

__device__ __forceinline__ int nthbit(unsigned int m, int k) {
    for (int i = 0; i < k; i++) m &= m - 1;
    return __ffs(m) - 1;
}

// ---- K0: per-anchor precompute + fg zeroing + per-chunk cost maxes (no global init needed) ----
// grid = BSZ * NCH; block (b, c) owns anchors [c*CHA, (c+1)*CHA) of batch b.
__global__ __launch_bounds__(256) void k_pre(
    const float* __restrict__ pd_bboxes, const float* __restrict__ gt_bboxes,
    float4* __restrict__ precomp, float4* __restrict__ rowpre,
    unsigned int* __restrict__ rowmax_c,    // [BSZ][NMAXG*3][NCH], written unconditionally
    unsigned int* __restrict__ fg,
    int* __restrict__ mc_count, int* __restrict__ cl_count)
{
    __shared__ float sr[CHA], sa[CHA], sq[CHA];     // pd_r, pa, r2 per chunk anchor
    __shared__ float rpx[NMAXG], rpy[NMAXG], rpz[NMAXG];
    __shared__ unsigned int lmax[NMAXG * 3];

    int b = blockIdx.x / NCH, c = blockIdx.x % NCH;
    int t = threadIdx.x, wv = t >> 6, lane = t & 63;
    int base = c * CHA;

    if (blockIdx.x == 0 && t == 0) { *mc_count = 0; *cl_count = 0; }

    for (int j = t; j < CHA; j += 256) {
        int a = base + j;
        fg[(size_t)b * NAA + a] = 0u;               // replaces the fg memset
        float4 p = ((const float4*)pd_bboxes)[(size_t)b * NAA + a];
        float w2 = p.z - p.x, h2 = p.w - p.y + 1e-7f;
        float r2 = w2 / h2;
        float pr = fminf(w2, h2) / fmaxf(w2, h2);
        float pa = w2 * h2;
        float4 q; q.x = pr; q.y = pa; q.z = r2; q.w = atanf(r2);
        precomp[(size_t)b * NAA + a] = q;
        sr[j] = pr; sa[j] = pa; sq[j] = r2;
    }
    if (t < NMAXG) {
        float4 g = ((const float4*)gt_bboxes)[b * NMAXG + t];
        float w1 = g.z - g.x, h1 = g.w - g.y + 1e-7f;
        float r1 = w1 / h1;
        float4 rp;
        rp.x = fminf(w1, h1) / fmaxf(w1, h1);
        rp.y = w1 * h1;
        rp.z = r1;
        rp.w = atanf(r1);
        if (c == 0) rowpre[b * NMAXG + t] = rp;
        rpx[t] = rp.x; rpy[t] = rp.y; rpz[t] = rp.z;
    }
    if (t < NMAXG * 3) lmax[t] = 0u;
    __syncthreads();

    // lane = row; waves stride the chunk's anchors (wave-uniform LDS addr = broadcast)
    float rx = rpx[lane], ry = rpy[lane], rz = rpz[lane];
    float ms = 0.0f, ma = 0.0f, mw = 0.0f;   // all comps in (0,1]
    for (int j = wv; j < CHA; j += 4) {
        float vr = sr[j], va = sa[j], vq = sq[j];
        float cs = 1.0f - fabsf(rx - vr) / fmaxf(rx, vr);
        float ca = 1.0f - fabsf(ry - va) / fmaxf(ry, va);
        float cw = fminf(rz, vq) / fmaxf(rz, vq);
        ms = fmaxf(ms, cs); ma = fmaxf(ma, ca); mw = fmaxf(mw, cw);
    }
    atomicMax(&lmax[lane * 3 + 0], __float_as_uint(ms));   // positive floats: bit order = value order
    atomicMax(&lmax[lane * 3 + 1], __float_as_uint(ma));
    atomicMax(&lmax[lane * 3 + 2], __float_as_uint(mw));
    __syncthreads();
    // per-chunk slot, written unconditionally -> no zero-init required
    if (t < NMAXG * 3) rowmax_c[((size_t)b * (NMAXG * 3) + t) * NCH + c] = lmax[t];
}

// ---- K1: one WAVE per (b,n) row: chunk-max reduce, candidate enumeration, top-13, claims ----
__global__ __launch_bounds__(256) void k_rows(
    const float* __restrict__ pd_scores, const float* __restrict__ pd_bboxes,
    const int* __restrict__ gt_labels, const float* __restrict__ gt_bboxes,
    const float* __restrict__ mask_gt,
    const float4* __restrict__ precomp, const float4* __restrict__ rowpre,
    const unsigned int* __restrict__ rowmax_c,
    float* __restrict__ rowmax_f,
    unsigned int* __restrict__ pos_align, unsigned int* __restrict__ pos_ov,
    unsigned int* __restrict__ fg,
    int* __restrict__ finaln, float* __restrict__ fnalign, float* __restrict__ fnov,
    int* __restrict__ mc_count, int* __restrict__ mlist,
    int* __restrict__ cl_count, int* __restrict__ clist)
{
    __shared__ unsigned long long keys[4][WCAP];
    __shared__ float ovs[4][WCAP];
    __shared__ int win_a[4][16];
    __shared__ float win_al[4][16], win_ov[4][16];
    __shared__ int nw[4];

    int t = threadIdx.x, wv = t >> 6, lane = t & 63;
    int row = blockIdx.x * 4 + wv;          // waves independent (no barriers)
    int b = row >> 6, n = row & 63;

    // this wave owns row: zero its pos accumulators (read by k_fin/k_out later)
    if (lane == 0) { pos_align[row] = 0u; pos_ov[row] = 0u; }

    // reduce per-chunk cost maxes (fmax associative -> bit-identical to single-pass max)
    float rmx[3];
    #pragma unroll
    for (int c3 = 0; c3 < 3; c3++) {
        float v = 0.0f;
        if (lane < NCH)
            v = __uint_as_float(rowmax_c[((size_t)b * (NMAXG * 3) + n * 3 + c3) * NCH + lane]);
        for (int o = 32; o; o >>= 1) v = fmaxf(v, __shfl_xor(v, o));
        rmx[c3] = v;
    }
    if (lane == 0) {   // dense copy for k_fin (valid for ALL rows, mask or not)
        rowmax_f[row * 3 + 0] = rmx[0];
        rowmax_f[row * 3 + 1] = rmx[1];
        rowmax_f[row * 3 + 2] = rmx[2];
    }

    if (mask_gt[row] <= 0.0f) return;       // masked row selects nothing

    float4 g  = ((const float4*)gt_bboxes)[row];
    float4 rp = rowpre[row];
    float dms = rmx[0] + 1e-7f, dma = rmx[1] + 1e-7f, dmw = rmx[2] + 1e-7f;

    // per-level in-gt index masks; anchors are exact floats (i+0.5)*{8,16,32}
    unsigned int xm[3], ym[3];
    int xlo[3], ylo[3], cx[3], cy[3];
    {
        const int LS[3] = {8, 16, 32};
        const int LN[3] = {80, 40, 20};
        #pragma unroll
        for (int l = 0; l < 3; l++) {
            float sf = (float)LS[l], inv = 1.0f / (float)LS[l];
            int nn = LN[l];
            int xl = (int)floorf(g.x * inv - 0.5f) - 1; if (xl < 0) xl = 0;
            int xh = (int)floorf(g.z * inv - 0.5f) + 1; if (xh > nn - 1) xh = nn - 1;
            int yl = (int)floorf(g.y * inv - 0.5f) - 1; if (yl < 0) yl = 0;
            int yh = (int)floorf(g.w * inv - 0.5f) + 1; if (yh > nn - 1) yh = nn - 1;
            bool ok = false;
            if (lane < 32) {
                int i = xl + lane;
                if (i <= xh) {
                    float ax = ((float)i + 0.5f) * sf;
                    ok = (ax - g.x > 1e-9f) && (g.z - ax > 1e-9f);  // reference float test
                }
            } else {
                int i = yl + (lane - 32);
                if (i <= yh) {
                    float ay = ((float)i + 0.5f) * sf;
                    ok = (ay - g.y > 1e-9f) && (g.w - ay > 1e-9f);
                }
            }
            unsigned long long bal = __ballot(ok);
            xm[l] = (unsigned int)bal; ym[l] = (unsigned int)(bal >> 32);
            xlo[l] = xl; ylo[l] = yl; cx[l] = __popc(xm[l]); cy[l] = __popc(ym[l]);
        }
    }
    int c0 = cx[0] * cy[0], c1 = cx[1] * cy[1], c2 = cx[2] * cy[2];
    int cnt = c0 + c1 + c2;                 // bound ~430 (gwh <= 140) < WCAP
    if (cnt > WCAP) cnt = WCAP;

    // metric at candidates (= exactly the in-gt anchors)
    int lbl = gt_labels[row];
    const float* sc = pd_scores + (size_t)b * NAA * NCC + lbl;
    const float4* pb = (const float4*)pd_bboxes + (size_t)b * NAA;
    const float4* pc = precomp + (size_t)b * NAA;
    int mpos = 0;
    for (int jb = 0; jb < cnt; jb += 64) {  // uniform trip count for ballot
        int j = jb + lane;
        bool act = j < cnt;
        float align = 0.0f;
        if (act) {
            int j2, XLO, YLO, CX, NN, BB; unsigned int XM, YM;
            if (j < c0)           { j2 = j;           XM = xm[0]; YM = ym[0]; XLO = xlo[0]; YLO = ylo[0]; CX = cx[0]; NN = 80; BB = 0; }
            else if (j < c0 + c1) { j2 = j - c0;      XM = xm[1]; YM = ym[1]; XLO = xlo[1]; YLO = ylo[1]; CX = cx[1]; NN = 40; BB = 6400; }
            else                  { j2 = j - c0 - c1; XM = xm[2]; YM = ym[2]; XLO = xlo[2]; YLO = ylo[2]; CX = cx[2]; NN = 20; BB = 8000; }
            int iyi = j2 / CX;
            int ixi = j2 - iyi * CX;
            int ix = XLO + nthbit(XM, ixi);
            int iy = YLO + nthbit(YM, iyi);
            int a = BB + iy * NN + ix;
            float4 p = pb[a];
            float4 q = pc[a];
            float cs = 1.0f - fabsf(rp.x - q.x) / fmaxf(rp.x, q.x);
            float ca = 1.0f - fabsf(rp.y - q.y) / fmaxf(rp.y, q.y);
            float cw = fminf(rp.z, q.z) / fmaxf(rp.z, q.z);
            float cost = ((cs / dms + cw / dmw) + ca / dma) / 3.0f;
            cost = fmaxf(cost, 0.0f);
            float ov = ciou_pre(g.x, g.y, g.z, g.w, p.x, p.y, p.z, p.w,
                                rp.y, q.y, q.w - rp.w);
            float s = sc[(size_t)a * NCC];
            float o2 = ov * ov, o3 = o2 * ov, ov6 = o3 * o3;
            align = (s * ov6) * cost;
            keys[wv][j] = ((unsigned long long)__float_as_uint(align) << 32)
                        | (unsigned long long)(0xFFFFFFFFu - (unsigned)a);
            ovs[wv][j] = ov;
        }
        unsigned long long bal = __ballot(align > 0.0f);
        mpos += __popcll(bal);              // wave-uniform
    }

    int bA = b * NAA;
    int nwin;
    if (mpos >= KTOP) {
        // 13 argmax rounds (value desc, index asc = lax.top_k tie-break); winners all positive
        for (int k = 0; k < KTOP; k++) {
            unsigned long long best = 0ull;
            for (int jb = 0; jb < cnt; jb += 64) {
                int j = jb + lane;
                if (j < cnt) { unsigned long long kk = keys[wv][j]; best = kk > best ? kk : best; }
            }
            for (int o = 32; o; o >>= 1) {
                unsigned long long ot = __shfl_xor(best, o);
                best = ot > best ? ot : best;
            }
            for (int jb = 0; jb < cnt; jb += 64) {
                int j = jb + lane;
                if (j < cnt && keys[wv][j] == best) {   // exactly one j (index embedded)
                    keys[wv][j] = 0ull;
                    win_a[wv][k]  = (int)(0xFFFFFFFFu - (unsigned)(best & 0xFFFFFFFFull));
                    win_al[wv][k] = __uint_as_float((unsigned)(best >> 32));
                    win_ov[wv][k] = ovs[wv][j];
                }
            }
        }
        nwin = KTOP;
    } else {
        // <13 positives: all positives + lowest-index zero anchors of the whole row
        // (only in-gt zeros survive the later mask); zero anchor a selected iff
        // (a - #positives_with_idx<a) < Z.
        if (lane == 0) nw[wv] = 0;
        int Z = KTOP - mpos;
        for (int jb = 0; jb < cnt; jb += 64) {
            int j = jb + lane;
            if (j < cnt) {
                unsigned long long kk = keys[wv][j];
                int a = (int)(0xFFFFFFFFu - (unsigned)(kk & 0xFFFFFFFFull));
                bool sel;
                if ((kk >> 32) != 0ull) {
                    sel = true;
                } else {
                    int pcb = 0;
                    for (int j2 = 0; j2 < cnt; j2++) {
                        unsigned long long k2 = keys[wv][j2];
                        if ((k2 >> 32) != 0ull) {
                            int a2 = (int)(0xFFFFFFFFu - (unsigned)(k2 & 0xFFFFFFFFull));
                            if (a2 < a) pcb++;
                        }
                    }
                    sel = (a - pcb) < Z;
                }
                if (sel) {
                    int p = atomicAdd(&nw[wv], 1);
                    win_a[wv][p]  = a;
                    win_al[wv][p] = __uint_as_float((unsigned)(kk >> 32));
                    win_ov[wv][p] = ovs[wv][j];
                }
            }
        }
        nwin = nw[wv];
    }

    // parallel claim: lanes 0..nwin-1 concurrent fg atomics; one list atomic per wave
    bool isclaim = false, ismulti = false;
    int gi = 0;
    if (lane < nwin) {
        gi = bA + win_a[wv][lane];
        unsigned old = atomicAdd(&fg[gi], 1u);
        if (old == 0u) {
            finaln[gi] = n; fnalign[gi] = win_al[wv][lane]; fnov[gi] = win_ov[wv][lane];
            isclaim = true;
        } else if (old == 1u) {
            ismulti = true;
        }
    }
    unsigned long long cb = __ballot(isclaim);
    unsigned long long mb = __ballot(ismulti);
    int cbase = 0, mbase = 0;
    if (lane == 0) {
        if (cb) cbase = atomicAdd(cl_count, __popcll(cb));
        if (mb) mbase = atomicAdd(mc_count, __popcll(mb));
    }
    cbase = __shfl(cbase, 0);
    mbase = __shfl(mbase, 0);
    unsigned long long below = (lane == 0) ? 0ull : (~0ull >> (64 - lane));
    if (isclaim) clist[cbase + __popcll(cb & below)] = gi;
    if (ismulti) mlist[mbase + __popcll(mb & below)] = gi;
}

// ---- K2 (fused k_multi + k_post): disjoint gi sets -> no ordering needed ----
__global__ __launch_bounds__(256) void k_fin(
    const float* __restrict__ pd_scores, const float* __restrict__ pd_bboxes,
    const int* __restrict__ gt_labels, const float* __restrict__ gt_bboxes,
    const float4* __restrict__ precomp, const float4* __restrict__ rowpre,
    const float* __restrict__ rowmax, const unsigned int* __restrict__ fg,
    const int* __restrict__ mc_count, const int* __restrict__ mlist,
    const int* __restrict__ cl_count, const int* __restrict__ clist,
    int* __restrict__ finaln, float* __restrict__ fnalign, float* __restrict__ fnov,
    unsigned int* __restrict__ pos_align, unsigned int* __restrict__ pos_ov)
{
    int lane = threadIdx.x & 63;

    // multi-claimed anchors: one wave each; 64 gts across 64 lanes
    int gwv = (blockIdx.x << 2) + (threadIdx.x >> 6);
    int nwv = gridDim.x << 2;
    int mc = *mc_count;
    for (int w = gwv; w < mc; w += nwv) {
        int gi = mlist[w];                          // b*NAA + a
        int b = gi / NAA;
        int rowb = (b << 6) + lane;                 // lane = gt index n
        const float4 p  = ((const float4*)pd_bboxes)[gi];
        const float4 q  = precomp[gi];              // pd_r, pa, r2, at2
        const float4 g  = ((const float4*)gt_bboxes)[rowb];
        const float4 rp = rowpre[rowb];             // gt_r, ga, r1, at1
        float ov = ciou_pre(g.x, g.y, g.z, g.w, p.x, p.y, p.z, p.w,
                            rp.y, q.y, q.w - rp.w);
        // argmax over n, first max wins: value desc, index asc
        unsigned long long key = ((unsigned long long)__float_as_uint(ov) << 32)
                               | (unsigned long long)(63 - lane);
        unsigned long long best = key;
        for (int o = 32; o; o >>= 1) {
            unsigned long long ot = __shfl_xor(best, o);
            best = ot > best ? ot : best;
        }
        int nstar = 63 - (int)(best & 63ull);
        if (lane == nstar) {
            float cs = 1.0f - fabsf(rp.x - q.x) / fmaxf(rp.x, q.x);
            float ca = 1.0f - fabsf(rp.y - q.y) / fmaxf(rp.y, q.y);
            float cw = fminf(rp.z, q.z) / fmaxf(rp.z, q.z);
            const float* rm = rowmax + rowb * 3;
            float cost = ((cs / (rm[0] + 1e-7f) + cw / (rm[2] + 1e-7f)) + ca / (rm[1] + 1e-7f)) / 3.0f;
            cost = fmaxf(cost, 0.0f);
            int lbl = gt_labels[rowb];
            float s = pd_scores[(size_t)gi * NCC + lbl];
            float o2 = ov * ov, o3 = o2 * ov, ov6 = o3 * o3;
            float align = (s * ov6) * cost;
            finaln[gi] = nstar;
            fnalign[gi] = align;
            atomicMax(&pos_align[rowb], __float_as_uint(align));
            atomicMax(&pos_ov[rowb], __float_as_uint(ov));
        }
    }

    // single-claimed anchors (fg==1): per-row pos maxes from k_rows-written values
    int gt = blockIdx.x * 256 + threadIdx.x;
    int gs = gridDim.x * 256;
    int cl = *cl_count;
    for (int i = gt; i < cl; i += gs) {
        int gi = clist[i];
        if (fg[gi] == 1u) {
            int b = gi / NAA;
            int r = (b << 6) + finaln[gi];
            atomicMax(&pos_align[r], __float_as_uint(fnalign[gi]));
            atomicMax(&pos_ov[r], __float_as_uint(fnov[gi]));
        }
    }
}

// ---- K3: write all outputs (labels, bboxes, full score rows incl. zeros, fg_mask) ----
__global__ __launch_bounds__(256) void k_out(
    const int* __restrict__ gt_labels, const float* __restrict__ gt_bboxes,
    const unsigned int* __restrict__ fg,
    const int* __restrict__ finaln, const float* __restrict__ fnalign,
    const unsigned int* __restrict__ pos_align, const unsigned int* __restrict__ pos_ov,
    float* __restrict__ out)
{
    int i = blockIdx.x * 256 + threadIdx.x;   // b*NAA + a
    if (i >= BSZ * NAA) return;
    int b = i / NAA;
    int nf = (fg[i] > 0u) ? finaln[i] : -1;
    int tgt = (nf >= 0) ? nf : 0;             // argmax of all-zero column = 0
    int lbl = gt_labels[(b << 6) + tgt];
    float4 g = ((const float4*)gt_bboxes)[(b << 6) + tgt];

    out[i] = (float)lbl;                                          // target_labels
    ((float4*)(out + (size_t)BSZ * NAA))[i] = g;                  // target_bboxes

    float* srow = out + (size_t)BSZ * NAA * 5 + (size_t)i * NCC;  // target_scores row
    float4 z; z.x = 0.0f; z.y = 0.0f; z.z = 0.0f; z.w = 0.0f;
    #pragma unroll
    for (int c4 = 0; c4 < NCC / 4; c4++) ((float4*)srow)[c4] = z;

    float* ofg = out + (size_t)BSZ * NAA * (5 + NCC);             // fg_mask
    if (nf >= 0) {
        float pa = __uint_as_float(pos_align[(b << 6) + nf]);
        float po = __uint_as_float(pos_ov[(b << 6) + nf]);
        srow[lbl] = (fnalign[i] * po) / (pa + 1e-9f);
        ofg[i] = 1.0f;
    } else {
        ofg[i] = 0.0f;
    }
}

extern "C" void kernel_launch(void* const* d_in, const int* in_sizes, int n_in,
                              void* d_out, int out_size, void* d_ws, size_t ws_size,
                              hipStream_t stream)
{
    const float* pd_scores = (const float*)d_in[0];
    const float* pd_bboxes = (const float*)d_in[1];
    const int*   gt_labels = (const int*)d_in[3];
    const float* gt_bboxes = (const float*)d_in[4];
    const float* mask_gt   = (const float*)d_in[5];
    float* out = (float*)d_out;

    char* ws = (char*)d_ws;
    const size_t NBA = (size_t)BSZ * NAA * 4;                 // 537600 B per per-anchor array
    size_t off = 0;
    float4*       precomp  = (float4*)(ws + off); off += (size_t)BSZ * NAA * 16;  // 2150400
    float4*       rowpre   = (float4*)(ws + off); off += BSZ * NMAXG * 16;        // 16384
    unsigned int* fg       = (unsigned int*)(ws + off); off += NBA;
    int*          finaln   = (int*)(ws + off);          off += NBA;
    float*        fnalign  = (float*)(ws + off);        off += NBA;
    float*        fnov     = (float*)(ws + off);        off += NBA;
    unsigned int* posal    = (unsigned int*)(ws + off); off += 4096;
    unsigned int* posov    = (unsigned int*)(ws + off); off += 4096;
    unsigned int* rowmax_c = (unsigned int*)(ws + off); off += (size_t)BSZ * NMAXG * 3 * NCH * 4; // 491520
    float*        rowmax_f = (float*)(ws + off);        off += 12288;
    int*          mc_count = (int*)(ws + off);
    int*          cl_count = (int*)(ws + off + 4);      off += 256;
    int*          mlist    = (int*)(ws + off);          off += MCMAX * 4;
    int*          clist    = (int*)(ws + off);          off += CLMAX * 4;

    // NO memsets: fg/counters zeroed by k_pre, posal/posov/rowmax_f by k_rows,
    // rowmax_c written unconditionally, finaln/fnalign/fnov gated by fg.

    k_pre<<<BSZ * NCH, 256, 0, stream>>>(pd_bboxes, gt_bboxes, precomp, rowpre,
                                         rowmax_c, fg, mc_count, cl_count);
    k_rows<<<BSZ * NMAXG / 4, 256, 0, stream>>>(pd_scores, pd_bboxes, gt_labels,
                                                gt_bboxes, mask_gt, precomp, rowpre,
                                                rowmax_c, rowmax_f, posal, posov, fg,
                                                finaln, fnalign, fnov,
                                                mc_count, mlist, cl_count, clist);
    k_fin<<<64, 256, 0, stream>>>(pd_scores, pd_bboxes, gt_labels, gt_bboxes,
                                  precomp, rowpre, rowmax_f, fg,
                                  mc_count, mlist, cl_count, clist,
                                  finaln, fnalign, fnov, posal, posov);
    int grid = (BSZ * NAA + 255) / 256;
    k_out<<<grid, 256, 0, stream>>>(gt_labels, gt_bboxes, fg, finaln, fnalign,
                                    posal, posov, out);
}